// Round 7
// baseline (565.159 us; speedup 1.0000x reference)
//
#include <hip/hip_runtime.h>

// LSTM B=2048,T=512,I=5,H=128 + linear -> [B,1], fp32 in/out.
// Round 7: 16 waves (4/SIMD), K-split. Wave pair (w, w+8) shares col-group w:
//   grp0 wave w   : h-cols 0..63   -> 8 MFMA/step
//   grp1 wave w+8 : h-cols 64..127 -> 8 MFMA/step, + x/bias chunk as a SEED
//                   MFMA computed during the PREVIOUS step's cell phase (xs is
//                   static -> no h dependency; moves 8 of 40 MFMA/SIMD off the
//                   post-barrier critical path).
// Partial gate tiles exchanged via LDS packed g-innermost (float4 per (n,m)):
// r6's bpermute+cndmask shuffle is gone; every lane owns exactly 1 cell
// (mcell = grp*4+q, col = wg*16+n) and reads its 4 gates as 2 ds_read_b128
// (+4 adds). Trans work now spread over 4 waves/SIMD for latency hiding.
// 2 barriers/step (pacc handoff, h handoff). VGPR must stay <=128 (16 waves
// co-resident) - round-1 spill lesson; seed/acc lifetimes disjoint.

#define HH 128
#define II 5
#define TT 512
#define BT 8
#define NT 1024
#define KS 136             // hbuf row stride in f16
#define XT (TT * 8 + 8)    // xs per-batch stride in f16
#define MP 9               // pacc m-dim pad (float4 units)

typedef __attribute__((ext_vector_type(8))) _Float16 half8;
typedef __attribute__((ext_vector_type(4))) float f32x4;

#define SIG(u) __builtin_amdgcn_rcpf(1.0f + __builtin_amdgcn_exp2f(u))

// One timestep. PB = h read buffer (compile-time), XNXT = xs offset of the
// NEXT step (for the seed), LAST = peeled final step (fp32 hsc write, no seed).
#define STEP(PB, XNXT, LAST) {                                                  \
    if (nmask) {                                                                \
        const _Float16* hp = hrd + (PB) * (BT * KS);                            \
        ah0 = *reinterpret_cast<const half8*>(hp);                              \
        ah1 = *reinterpret_cast<const half8*>(hp + 32);                         \
    }                                                                           \
    f32x4 acc[4];                                                               \
    _Pragma("unroll")                                                           \
    for (int g = 0; g < 4; ++g) {                                               \
        acc[g] = __builtin_amdgcn_mfma_f32_16x16x32_f16(ah0, wf[g][0], seed[g], 0, 0, 0); \
        acc[g] = __builtin_amdgcn_mfma_f32_16x16x32_f16(ah1, wf[g][1], acc[g],  0, 0, 0); \
    }                                                                           \
    if (q < 2) {                                                                \
        _Pragma("unroll")                                                       \
        for (int r = 0; r < 4; ++r) {                                           \
            f32x4 pv = {acc[0][r], acc[1][r], acc[2][r], acc[3][r]};            \
            pwr[r] = pv;                                                        \
        }                                                                       \
    }                                                                           \
    __syncthreads();                      /* barrier B: pacc ready */           \
    f32x4 p0 = prd0[0], p1 = prd1[0];                                           \
    float iv = SIG(p0[0] + p1[0]);                                              \
    float fv = SIG(p0[1] + p1[1]);                                              \
    float gv = 1.0f - 2.0f * SIG(p0[2] + p1[2]);                                \
    float ov = SIG(p0[3] + p1[3]);                                              \
    cc0 = fv * cc0 + iv * gv;                                                   \
    float hv = ov * (1.0f - 2.0f * SIG(2.88539008f * cc0));                     \
    if (LAST) {                                                                 \
        hsc[mcell][hcol] = hv;                                                  \
    } else {                                                                    \
        hwr[((PB) ^ 1) * (BT * KS)] = (_Float16)hv;                             \
        if (grp) {                        /* seed for NEXT step: x/bias MFMA */ \
            if (xmask) ax = *reinterpret_cast<const half8*>(xcur + (XNXT));     \
            _Pragma("unroll")                                                   \
            for (int g = 0; g < 4; ++g)                                         \
                seed[g] = __builtin_amdgcn_mfma_f32_16x16x32_f16(ax, wf[g][2], zero4, 0, 0, 0); \
        }                                                                       \
    }                                                                           \
    __syncthreads();                      /* barrier A: h(t+1) ready */         \
}

__global__ __launch_bounds__(NT)
void lstm_r7(const float* __restrict__ x,      // [B,T,I]
             const float* __restrict__ W_ih,   // [4H,I]
             const float* __restrict__ W_hh,   // [4H,H]
             const float* __restrict__ b_ih,   // [4H]
             const float* __restrict__ b_hh,   // [4H]
             const float* __restrict__ W_lin,  // [H]
             const float* __restrict__ b_lin,  // [1]
             float* __restrict__ out,          // [B]
             int B)
{
    __shared__ __align__(16) _Float16 hbuf[2][BT][KS];   // 4.4 KB dbuf h
    __shared__ __align__(16) _Float16 xs[BT * XT];       // 65.7 KB staged x
    __shared__ f32x4 pacc[2][8][16][MP];                 // 36.9 KB gate partials
    __shared__ float hsc[BT][HH + 4];                    // final fp32 h

    const int tid  = threadIdx.x;
    const int b0   = blockIdx.x * BT;
    const int lane = tid & 63;
    const int w    = tid >> 6;        // 0..15
    const int grp  = w >> 3;          // K-half
    const int wg   = w & 7;           // col group
    const int n    = lane & 15;       // A row (batch) / D col
    const int q    = lane >> 4;
    const int q8   = q * 8;
    const int hcol = wg * 16 + n;     // this wave's gate columns

    // ---- W frags, f16, B-layout, activation scale folded --------------------
    // grp0: W_hh k 0..63 (2 chunks); grp1: W_hh k 64..127 + [W_ih|bias] chunk.
    half8 wf[4][3];
    #pragma unroll
    for (int g = 0; g < 4; ++g) {
        const float sc = (g == 2) ? 2.88539008f : -1.44269504f;
        const int j = g * HH + hcol;
        #pragma unroll
        for (int c = 0; c < 2; ++c) {
            const float* p = W_hh + (size_t)j * HH + grp * 64 + c * 32 + q8;
            #pragma unroll
            for (int e = 0; e < 8; ++e) wf[g][c][e] = (_Float16)(p[e] * sc);
        }
        #pragma unroll
        for (int e = 0; e < 8; ++e) {
            const int k = q8 + e;
            float v = 0.0f;
            if (k < II)       v = W_ih[j * II + k];
            else if (k == II) v = b_ih[j] + b_hh[j];
            wf[g][2][e] = (_Float16)(v * sc);   // used by grp1 only
        }
    }

    // ---- zero LDS -----------------------------------------------------------
    for (int idx = tid; idx < 2 * BT * KS; idx += NT)
        (&hbuf[0][0][0])[idx] = (_Float16)0.0f;
    for (int idx = tid; idx < BT * XT; idx += NT)
        xs[idx] = (_Float16)0.0f;
    __syncthreads();

    // ---- stage x (f16) + constant-1.0 bias column in slot 5 -----------------
    {
        const int lb = tid & 127, bb = tid >> 7;
        if (b0 + bb < B) {
            const float* xb = x + (size_t)(b0 + bb) * TT * II;
            for (int e = lb * 4; e < TT * II; e += 512) {
                float4 v = *reinterpret_cast<const float4*>(xb + e);
                float vv[4] = {v.x, v.y, v.z, v.w};
                #pragma unroll
                for (int u = 0; u < 4; ++u) {
                    const int ee = e + u;
                    xs[bb * XT + (ee / 5) * 8 + (ee % 5)] = (_Float16)vv[u];
                }
            }
        }
        for (int s = tid; s < BT * TT; s += NT)
            xs[(s >> 9) * XT + (s & 511) * 8 + 5] = (_Float16)1.0f;
    }
    __syncthreads();

    // ---- loop-invariant state ----------------------------------------------
    const int mcell = grp * 4 + q;                  // this lane's cell row
    float cc0 = 0.f;
    const f32x4 zero4 = {0.f, 0.f, 0.f, 0.f};
    const bool nmask = (n < BT);
    const bool xmask = (q == 0) && nmask;           // grp1 x-loader lanes
    const _Float16* hrd = &hbuf[0][0][0] + n * KS + grp * 64 + q8;
    _Float16*       hwr = &hbuf[0][0][0] + mcell * KS + hcol;
    const _Float16* xcur = &xs[0] + n * XT;         // advances 16/pair
    f32x4* pwr  = &pacc[grp][wg][n][q * 4];         // partial write (q<2)
    f32x4* prd0 = &pacc[0][wg][n][mcell];           // cell gate reads
    f32x4* prd1 = &pacc[1][wg][n][mcell];

    // persistent A-frags; masked lanes keep zeros forever
    half8 ax, ah0, ah1;
    #pragma unroll
    for (int e = 0; e < 8; ++e) ax[e] = (_Float16)0.0f;
    ah0 = ax; ah1 = ax;

    // seed(0): grp1's x/bias MFMA for t=0; grp0 seed stays zero forever
    f32x4 seed[4] = {zero4, zero4, zero4, zero4};
    if (grp) {
        if (xmask) ax = *reinterpret_cast<const half8*>(xcur);
        #pragma unroll
        for (int g = 0; g < 4; ++g)
            seed[g] = __builtin_amdgcn_mfma_f32_16x16x32_f16(ax, wf[g][2], zero4, 0, 0, 0);
    }

    #pragma unroll 1
    for (int t = 0; t < TT - 2; t += 2) {
        STEP(0, 8, false);
        STEP(1, 16, false);
        xcur += 16;
    }
    STEP(0, 8, false);     // t = 510
    STEP(1, 0, true);      // t = 511, peeled: fp32 hsc, no seed

    // ---- epilogue: out[b0+w] = hsc[w,:] . W_lin + b_lin (waves 0..7) --------
    if (w < 8) {
        float p = hsc[w][lane] * W_lin[lane] + hsc[w][lane + 64] * W_lin[lane + 64];
        #pragma unroll
        for (int off = 32; off > 0; off >>= 1) p += __shfl_down(p, off, 64);
        if (lane == 0 && (b0 + w) < B) out[b0 + w] = p + b_lin[0];
    }
}

extern "C" void kernel_launch(void* const* d_in, const int* in_sizes, int n_in,
                              void* d_out, int out_size, void* d_ws, size_t ws_size,
                              hipStream_t stream) {
    const float* x     = (const float*)d_in[0];
    const float* W_ih  = (const float*)d_in[1];
    const float* W_hh  = (const float*)d_in[2];
    const float* b_ih  = (const float*)d_in[3];
    const float* b_hh  = (const float*)d_in[4];
    const float* W_lin = (const float*)d_in[5];
    const float* b_lin = (const float*)d_in[6];
    float* out = (float*)d_out;

    const int B = in_sizes[0] / (TT * II);          // 2048
    const int grid = (B + BT - 1) / BT;             // 256 blocks, 1 per CU
    lstm_r7<<<grid, NT, 0, stream>>>(x, W_ih, W_hh, b_ih, b_hh,
                                     W_lin, b_lin, out, B);
}